// Round 9
// baseline (478.718 us; speedup 1.0000x reference)
//
#include <hip/hip_runtime.h>
#include <hip/hip_bf16.h>
#include <hip/hip_cooperative_groups.h>

namespace cg = cooperative_groups;

#define N_NODES 50000
#define IN_DIM 256
#define OUT_DIM 128
#define ODIM2 256        // mu(128) + logstd(128) concatenated
#define NEDGE 800000
#define MAX_LOGSTD 10.0f
#define NBLK 196         // ceil(50000/256)
#define PREP_BLOCKS 512
#define GEMM_BLOCKS 512
#define GEMM_TILES 1563  // ceil(50000/32)

typedef short bf16x8 __attribute__((ext_vector_type(8)));
typedef float f32x4  __attribute__((ext_vector_type(4)));

__device__ __forceinline__ float b2f(unsigned short u) {
    union { unsigned int i; float f; } v; v.i = ((unsigned int)u) << 16; return v.f;
}
__device__ __forceinline__ unsigned short f2b(float f) {
    union { float f; unsigned int i; } v; v.f = f;
    unsigned int x = v.i;
    unsigned int r = (x + 0x7fffu + ((x >> 16) & 1u)) >> 16;
    return (unsigned short)r;
}
__device__ __forceinline__ bool edges_are_i64(const int* raw) {
    bool is64 = true;
    #pragma unroll
    for (int i = 0; i < 8; i++) if (raw[2 * i + 1] != 0) is64 = false;
    return is64;
}

// ONE cooperative kernel: zero cnt + wconv | histogram | 3-phase scan (+dinv) | fill.
// Blocks stay resident across grid.sync() so LDS scan partials persist.
__global__ __launch_bounds__(256) void k_prep(
    const int* __restrict__ raw, const float* __restrict__ Wmu,
    const float* __restrict__ Wls, int* __restrict__ cnt,
    int* __restrict__ row_start, int* __restrict__ pos,
    float* __restrict__ dinv, int* __restrict__ csr,
    unsigned short* __restrict__ Wp, int* __restrict__ bsum)
{
    cg::grid_group grid = cg::this_grid();
    const int tid  = threadIdx.x;
    const int bid  = blockIdx.x;
    const int gtid = bid * 256 + tid;
    const int nthr = PREP_BLOCKS * 256;

    __shared__ int s[256];    // local inclusive scan (persists to phase B3)
    __shared__ int t2[256];   // block-0 scratch for block-sum scan

    // ---- A0: zero cnt + weight conversion (independent work) ----
    for (int i = gtid; i < N_NODES; i += nthr) cnt[i] = 0;
    if (gtid < 8192) {
        int i = gtid;
        int lane = i & 63;
        int kk   = (i >> 6) & 7;
        int tile = i >> 9;
        int k0 = kk * 32 + (lane >> 4) * 8;
        int n  = tile * 16 + (lane & 15);
        const float* W = (n < 128) ? (Wmu + n) : (Wls + (n - 128));
        unsigned short o[8];
        #pragma unroll
        for (int j = 0; j < 8; j++) o[j] = f2b(W[(size_t)(k0 + j) * OUT_DIM]);
        ushort4 lo = { o[0], o[1], o[2], o[3] };
        ushort4 hi = { o[4], o[5], o[6], o[7] };
        *(ushort4*)(Wp + (size_t)i * 8)     = lo;
        *(ushort4*)(Wp + (size_t)i * 8 + 4) = hi;
    }
    const bool is64 = edges_are_i64(raw);
    grid.sync();

    // ---- A1: dst histogram ----
    for (int e = gtid; e < NEDGE; e += nthr) {
        int dst = is64 ? raw[2 * (NEDGE + e)] : raw[NEDGE + e];
        atomicAdd(&cnt[dst], 1);
    }
    grid.sync();

    // ---- B1: blocks < NBLK do LDS inclusive scan of their 256 counts ----
    int c = 0;
    if (bid < NBLK) {
        int idx = bid * 256 + tid;
        c = (idx < N_NODES) ? cnt[idx] : 0;
        s[tid] = c;
        __syncthreads();
        for (int o = 1; o < 256; o <<= 1) {
            int v = (tid >= o) ? s[tid - o] : 0;
            __syncthreads();
            s[tid] += v;
            __syncthreads();
        }
        if (tid == 255) bsum[bid] = s[255];
    }
    grid.sync();

    // ---- B2: block 0 turns bsum into exclusive block offsets (in place) ----
    if (bid == 0) {
        int v = (tid < NBLK) ? bsum[tid] : 0;
        t2[tid] = v;
        __syncthreads();
        for (int o = 1; o < 256; o <<= 1) {
            int w = (tid >= o) ? t2[tid - o] : 0;
            __syncthreads();
            t2[tid] += w;
            __syncthreads();
        }
        if (tid < NBLK) bsum[tid] = t2[tid] - v;
    }
    grid.sync();

    // ---- B3: row_start / pos / dinv ----
    if (bid < NBLK) {
        int idx = bid * 256 + tid;
        int excl = bsum[bid] + s[tid] - c;
        if (idx < N_NODES) {
            row_start[idx] = excl;
            pos[idx] = excl;
            dinv[idx] = rsqrtf((float)c + 1.0f);
        }
        if (idx == N_NODES - 1) row_start[N_NODES] = NEDGE;
    }
    grid.sync();

    // ---- C: bin edges by dst ----
    for (int e = gtid; e < NEDGE; e += nthr) {
        int src = is64 ? raw[2 * e] : raw[e];
        int dst = is64 ? raw[2 * (NEDGE + e)] : raw[NEDGE + e];
        int p = atomicAdd(&pos[dst], 1);
        csr[p] = src;
    }
}

// Persistent MFMA GEMM -> hs (PRE-SCALED): hs[n][c] = dinv[n]*(x@W)[n][c] (bf16).
// 32-row tiles grid-strided by 512 blocks; B fragments loaded once per BLOCK.
__global__ __launch_bounds__(256, 2) void k_gemm_mfma(
    const float* __restrict__ x, const unsigned short* __restrict__ Wp,
    const float* __restrict__ dinv, unsigned short* __restrict__ hs)
{
    __shared__ unsigned short xs[32 * 256];   // 16 KB, swizzled
    const int tid  = threadIdx.x;
    const int lane = tid & 63;
    const int w    = tid >> 6;

    // B fragments for this wave's 4 col-tiles, all 8 k-steps: loaded ONCE.
    bf16x8 breg[4][8];
    #pragma unroll
    for (int t = 0; t < 4; t++)
        #pragma unroll
        for (int kk = 0; kk < 8; kk++)
            breg[t][kk] = ((const bf16x8*)Wp)[((4 * w + t) * 8 + kk) * 64 + lane];

    for (int tile = blockIdx.x; tile < GEMM_TILES; tile += GEMM_BLOCKS) {
        const int row0 = tile * 32;

        // stage 32x256 f32 -> bf16 (XOR-swizzled rows)
        #pragma unroll
        for (int i = 0; i < 8; i++) {
            int f   = i * 256 + tid;
            int row = f >> 6;
            int c4  = f & 63;
            int grow = row0 + row;
            float4 v = make_float4(0.f, 0.f, 0.f, 0.f);
            if (grow < N_NODES) v = *(const float4*)(x + (size_t)grow * IN_DIM + c4 * 4);
            ushort4 b = { f2b(v.x), f2b(v.y), f2b(v.z), f2b(v.w) };
            unsigned int byte = (unsigned)(row * 512 + c4 * 8);
            byte ^= (unsigned)((row & 7) << 4);
            *(ushort4*)((char*)xs + byte) = b;
        }
        __syncthreads();

        #pragma unroll
        for (int sub = 0; sub < 2; sub++) {
            const int arow = sub * 16 + (lane & 15);
            const unsigned int abase = (unsigned)(arow * 512 + (lane >> 4) * 16);
            const unsigned int axor  = (unsigned)((arow & 7) << 4);

            bf16x8 a[8];
            #pragma unroll
            for (int kk = 0; kk < 8; kk++)
                a[kk] = *(const bf16x8*)((const char*)xs + ((abase + kk * 64) ^ axor));

            f32x4 acc[4];
            #pragma unroll
            for (int t = 0; t < 4; t++) acc[t] = (f32x4){0.f, 0.f, 0.f, 0.f};

            #pragma unroll
            for (int kk = 0; kk < 8; kk++)
                #pragma unroll
                for (int t = 0; t < 4; t++)
                    acc[t] = __builtin_amdgcn_mfma_f32_16x16x32_bf16(a[kk], breg[t][kk],
                                                                     acc[t], 0, 0, 0);

            // C/D layout: col=lane&15, row=(lane>>4)*4+reg; scale by dinv on store
            const int rbase = row0 + sub * 16 + (lane >> 4) * 4;
            const int cl = lane & 15;
            float dv[4];
            #pragma unroll
            for (int r = 0; r < 4; r++)
                dv[r] = (rbase + r < N_NODES) ? dinv[rbase + r] : 0.0f;
            #pragma unroll
            for (int t = 0; t < 4; t++) {
                int col = (4 * w + t) * 16 + cl;
                #pragma unroll
                for (int r = 0; r < 4; r++) {
                    int row = rbase + r;
                    if (row < N_NODES)
                        hs[(size_t)row * ODIM2 + col] = f2b(acc[t][r] * dv[r]);
                }
            }
        }
        __syncthreads();   // xs reused next tile
    }
}

#define ACC4(v) { a0 += b2f((v).x); a1 += b2f((v).y); a2 += b2f((v).z); a3 += b2f((v).w); }

// Wave-per-node pull gather over PRE-SCALED hs: pure accumulate, 16 edges in flight.
// out = dinv_d * (sum_{s in N(d)} hs[s] + hs[d]).
__global__ __launch_bounds__(256) void k_gather(
    const int* __restrict__ row_start, const int* __restrict__ csr,
    const float* __restrict__ dinv, const unsigned short* __restrict__ hs,
    const float* __restrict__ eps, const float* __restrict__ bmu,
    const float* __restrict__ bls, float* __restrict__ z)
{
    const int tid  = threadIdx.x;
    const int n    = blockIdx.x * 4 + (tid >> 6);
    const int lane = tid & 63;
    const float dn = dinv[n];

    float a0, a1, a2, a3;
    {   // self-loop seed: hs[n] (scaled by dn at the end)
        ushort4 v = ((const ushort4*)(hs + (size_t)n * ODIM2))[lane];
        a0 = b2f(v.x); a1 = b2f(v.y); a2 = b2f(v.z); a3 = b2f(v.w);
    }

    const int beg = row_start[n];
    const int end = row_start[n + 1];
    int j = beg;
    for (; j < end && (j & 3); j++) {              // align to int4
        int s = csr[j];
        ushort4 v = ((const ushort4*)(hs + (size_t)s * ODIM2))[lane];
        ACC4(v);
    }
    for (; j + 16 <= end; j += 16) {               // 16 gathers in flight
        int4 sA = *(const int4*)(csr + j);
        int4 sB = *(const int4*)(csr + j + 4);
        int4 sC = *(const int4*)(csr + j + 8);
        int4 sD = *(const int4*)(csr + j + 12);
        ushort4 v0 = ((const ushort4*)(hs + (size_t)sA.x * ODIM2))[lane];
        ushort4 v1 = ((const ushort4*)(hs + (size_t)sA.y * ODIM2))[lane];
        ushort4 v2 = ((const ushort4*)(hs + (size_t)sA.z * ODIM2))[lane];
        ushort4 v3 = ((const ushort4*)(hs + (size_t)sA.w * ODIM2))[lane];
        ushort4 v4 = ((const ushort4*)(hs + (size_t)sB.x * ODIM2))[lane];
        ushort4 v5 = ((const ushort4*)(hs + (size_t)sB.y * ODIM2))[lane];
        ushort4 v6 = ((const ushort4*)(hs + (size_t)sB.z * ODIM2))[lane];
        ushort4 v7 = ((const ushort4*)(hs + (size_t)sB.w * ODIM2))[lane];
        ushort4 v8 = ((const ushort4*)(hs + (size_t)sC.x * ODIM2))[lane];
        ushort4 v9 = ((const ushort4*)(hs + (size_t)sC.y * ODIM2))[lane];
        ushort4 va = ((const ushort4*)(hs + (size_t)sC.z * ODIM2))[lane];
        ushort4 vb = ((const ushort4*)(hs + (size_t)sC.w * ODIM2))[lane];
        ushort4 vc = ((const ushort4*)(hs + (size_t)sD.x * ODIM2))[lane];
        ushort4 vd = ((const ushort4*)(hs + (size_t)sD.y * ODIM2))[lane];
        ushort4 ve = ((const ushort4*)(hs + (size_t)sD.z * ODIM2))[lane];
        ushort4 vf = ((const ushort4*)(hs + (size_t)sD.w * ODIM2))[lane];
        ACC4(v0); ACC4(v1); ACC4(v2); ACC4(v3);
        ACC4(v4); ACC4(v5); ACC4(v6); ACC4(v7);
        ACC4(v8); ACC4(v9); ACC4(va); ACC4(vb);
        ACC4(vc); ACC4(vd); ACC4(ve); ACC4(vf);
    }
    if (j + 8 <= end) {
        int4 sA = *(const int4*)(csr + j);
        int4 sB = *(const int4*)(csr + j + 4);
        ushort4 v0 = ((const ushort4*)(hs + (size_t)sA.x * ODIM2))[lane];
        ushort4 v1 = ((const ushort4*)(hs + (size_t)sA.y * ODIM2))[lane];
        ushort4 v2 = ((const ushort4*)(hs + (size_t)sA.z * ODIM2))[lane];
        ushort4 v3 = ((const ushort4*)(hs + (size_t)sA.w * ODIM2))[lane];
        ushort4 v4 = ((const ushort4*)(hs + (size_t)sB.x * ODIM2))[lane];
        ushort4 v5 = ((const ushort4*)(hs + (size_t)sB.y * ODIM2))[lane];
        ushort4 v6 = ((const ushort4*)(hs + (size_t)sB.z * ODIM2))[lane];
        ushort4 v7 = ((const ushort4*)(hs + (size_t)sB.w * ODIM2))[lane];
        ACC4(v0); ACC4(v1); ACC4(v2); ACC4(v3);
        ACC4(v4); ACC4(v5); ACC4(v6); ACC4(v7);
        j += 8;
    }
    if (j + 4 <= end) {
        int4 sA = *(const int4*)(csr + j);
        ushort4 v0 = ((const ushort4*)(hs + (size_t)sA.x * ODIM2))[lane];
        ushort4 v1 = ((const ushort4*)(hs + (size_t)sA.y * ODIM2))[lane];
        ushort4 v2 = ((const ushort4*)(hs + (size_t)sA.z * ODIM2))[lane];
        ushort4 v3 = ((const ushort4*)(hs + (size_t)sA.w * ODIM2))[lane];
        ACC4(v0); ACC4(v1); ACC4(v2); ACC4(v3);
        j += 4;
    }
    for (; j < end; j++) {
        int s = csr[j];
        ushort4 v = ((const ushort4*)(hs + (size_t)s * ODIM2))[lane];
        ACC4(v);
    }

    float l0 = __shfl(a0, lane | 32);
    float l1 = __shfl(a1, lane | 32);
    float l2 = __shfl(a2, lane | 32);
    float l3 = __shfl(a3, lane | 32);

    if (lane < 32) {
        int c = lane * 4;
        float4 ep = *(const float4*)(eps + (size_t)n * OUT_DIM + c);
        float4 bm = *(const float4*)(bmu + c);
        float4 bl = *(const float4*)(bls + c);
        float4 o;
        o.x = dn * a0 + bm.x + ep.x * expf(fminf(dn * l0 + bl.x, MAX_LOGSTD));
        o.y = dn * a1 + bm.y + ep.y * expf(fminf(dn * l1 + bl.y, MAX_LOGSTD));
        o.z = dn * a2 + bm.z + ep.z * expf(fminf(dn * l2 + bl.z, MAX_LOGSTD));
        o.w = dn * a3 + bm.w + ep.w * expf(fminf(dn * l3 + bl.w, MAX_LOGSTD));
        *(float4*)(z + (size_t)n * OUT_DIM + c) = o;
    }
}

extern "C" void kernel_launch(void* const* d_in, const int* in_sizes, int n_in,
                              void* d_out, int out_size, void* d_ws, size_t ws_size,
                              hipStream_t stream) {
    const float* x   = (const float*)d_in[0];
    const int*   ei  = (const int*)  d_in[1];
    const float* Wmu = (const float*)d_in[2];
    const float* bmu = (const float*)d_in[3];
    const float* Wls = (const float*)d_in[4];
    const float* bls = (const float*)d_in[5];
    const float* eps = (const float*)d_in[6];
    float* z = (float*)d_out;

    char* ws = (char*)d_ws;
    size_t off = 0;
    auto alloc = [&](size_t bytes) {
        void* p = ws + off;
        off += (bytes + 255) & ~(size_t)255;
        return p;
    };
    int*   cnt       = (int*)  alloc((size_t)N_NODES * 4);
    float* dinv      = (float*)alloc((size_t)N_NODES * 4);
    int*   row_start = (int*)  alloc((size_t)(N_NODES + 1) * 4);
    int*   pos       = (int*)  alloc((size_t)N_NODES * 4);
    int*   csr       = (int*)  alloc((size_t)NEDGE * 4);
    int*   bsum      = (int*)  alloc((size_t)NBLK * 4);
    unsigned short* hs = (unsigned short*)alloc((size_t)N_NODES * ODIM2 * 2);
    unsigned short* Wp = (unsigned short*)alloc((size_t)65536 * 2);

    void* prep_args[] = { (void*)&ei, (void*)&Wmu, (void*)&Wls, (void*)&cnt,
                          (void*)&row_start, (void*)&pos, (void*)&dinv,
                          (void*)&csr, (void*)&Wp, (void*)&bsum };
    hipLaunchCooperativeKernel((void*)k_prep, dim3(PREP_BLOCKS), dim3(256),
                               prep_args, 0, stream);

    k_gemm_mfma<<<GEMM_BLOCKS, 256, 0, stream>>>(x, Wp, dinv, hs);
    k_gather   <<<N_NODES / 4, 256, 0, stream>>>(row_start, csr, dinv, hs,
                                                 eps, bmu, bls, z);
}

// Round 10
// 212.764 us; speedup vs baseline: 2.2500x; 2.2500x over previous
//
#include <hip/hip_runtime.h>
#include <hip/hip_bf16.h>

#define N_NODES 50000
#define IN_DIM 256
#define OUT_DIM 128
#define ODIM2 256        // mu(128) + logstd(128) concatenated
#define NEDGE 800000
#define MAX_LOGSTD 10.0f
#define NBLK 196         // ceil(50000/256)

typedef short bf16x8 __attribute__((ext_vector_type(8)));
typedef float f32x4  __attribute__((ext_vector_type(4)));

__device__ __forceinline__ float b2f(unsigned short u) {
    union { unsigned int i; float f; } v; v.i = ((unsigned int)u) << 16; return v.f;
}
__device__ __forceinline__ unsigned short f2b(float f) {
    union { float f; unsigned int i; } v; v.f = f;
    unsigned int x = v.i;
    unsigned int r = (x + 0x7fffu + ((x >> 16) & 1u)) >> 16;
    return (unsigned short)r;
}
__device__ __forceinline__ bool edges_are_i64(const int* raw) {
    bool is64 = true;
    #pragma unroll
    for (int i = 0; i < 8; i++) if (raw[2 * i + 1] != 0) is64 = false;
    return is64;
}

// dst histogram, 2 edges/thread, vectorized raw reads (int64 or int32 layout)
__global__ void k_count(const int* __restrict__ raw, int* __restrict__ cnt) {
    bool is64 = edges_are_i64(raw);
    int e2 = blockIdx.x * blockDim.x + threadIdx.x;   // edge-pair index
    if (e2 < NEDGE / 2) {
        int d0, d1;
        if (is64) {
            int4 d = *(const int4*)(raw + 2 * NEDGE + 4 * e2);
            d0 = d.x; d1 = d.z;
        } else {
            int2 d = *(const int2*)(raw + NEDGE + 2 * e2);
            d0 = d.x; d1 = d.y;
        }
        atomicAdd(&cnt[d0], 1);
        atomicAdd(&cnt[d1], 1);
    }
}

// Phase 1: per-block (256 counts) sums
__global__ __launch_bounds__(256) void k_blocksum(const int* __restrict__ cnt,
                                                  int* __restrict__ bsum) {
    int idx = blockIdx.x * 256 + threadIdx.x;
    int v = (idx < N_NODES) ? cnt[idx] : 0;
    #pragma unroll
    for (int o = 32; o > 0; o >>= 1) v += __shfl_down(v, o);
    __shared__ int wsum[4];
    int lane = threadIdx.x & 63, w = threadIdx.x >> 6;
    if (lane == 0) wsum[w] = v;
    __syncthreads();
    if (threadIdx.x == 0) bsum[blockIdx.x] = wsum[0] + wsum[1] + wsum[2] + wsum[3];
}

// Phase 2: scan 196 block sums -> exclusive block offsets
__global__ __launch_bounds__(256) void k_scanblocks(const int* __restrict__ bsum,
                                                    int* __restrict__ boff) {
    __shared__ int s[256];
    int t = threadIdx.x;
    s[t] = (t < NBLK) ? bsum[t] : 0;
    __syncthreads();
    for (int o = 1; o < 256; o <<= 1) {
        int v = (t >= o) ? s[t - o] : 0;
        __syncthreads();
        s[t] += v;
        __syncthreads();
    }
    if (t < NBLK) boff[t] = (t == 0) ? 0 : s[t - 1];
}

// Phase 3: in-block exclusive scan + offset -> row_start, pos, dinv.
// Blocks 0..31 additionally pack concat(Wmu,Wls) into B-fragment bf16 layout:
// Wp[((tile*8+kk)*64+lane)*8 + j] = W[kk*32+(lane>>4)*8+j][tile*16+(lane&15)]
__global__ __launch_bounds__(256) void k_apply(const int* __restrict__ cnt,
                                               const int* __restrict__ boff,
                                               int* __restrict__ row_start,
                                               int* __restrict__ pos,
                                               float* __restrict__ dinv,
                                               const float* __restrict__ Wmu,
                                               const float* __restrict__ Wls,
                                               unsigned short* __restrict__ Wp) {
    __shared__ int s[256];
    int t = threadIdx.x;
    int idx = blockIdx.x * 256 + t;
    int c = (idx < N_NODES) ? cnt[idx] : 0;
    s[t] = c;
    __syncthreads();
    for (int o = 1; o < 256; o <<= 1) {
        int v = (t >= o) ? s[t - o] : 0;
        __syncthreads();
        s[t] += v;
        __syncthreads();
    }
    int excl = boff[blockIdx.x] + s[t] - c;
    if (idx < N_NODES) {
        row_start[idx] = excl;
        pos[idx] = excl;
        dinv[idx] = rsqrtf((float)c + 1.0f);
    }
    if (idx == N_NODES - 1) row_start[N_NODES] = NEDGE;

    if (blockIdx.x < 32) {            // fused weight conversion (8192 jobs)
        int i = blockIdx.x * 256 + t;
        int lane = i & 63;
        int kk   = (i >> 6) & 7;
        int tile = i >> 9;
        int k0 = kk * 32 + (lane >> 4) * 8;
        int n  = tile * 16 + (lane & 15);
        const float* W = (n < 128) ? (Wmu + n) : (Wls + (n - 128));
        unsigned short o[8];
        #pragma unroll
        for (int j = 0; j < 8; j++) o[j] = f2b(W[(size_t)(k0 + j) * OUT_DIM]);
        ushort4 lo = { o[0], o[1], o[2], o[3] };
        ushort4 hi = { o[4], o[5], o[6], o[7] };
        *(ushort4*)(Wp + (size_t)i * 8)     = lo;
        *(ushort4*)(Wp + (size_t)i * 8 + 4) = hi;
    }
}

// Bin edges by dst, 2 edges/thread, vectorized raw reads
__global__ void k_fill(const int* __restrict__ raw, int* __restrict__ pos,
                       int* __restrict__ csr) {
    bool is64 = edges_are_i64(raw);
    int e2 = blockIdx.x * blockDim.x + threadIdx.x;
    if (e2 < NEDGE / 2) {
        int s0, s1, d0, d1;
        if (is64) {
            int4 sv = *(const int4*)(raw + 4 * e2);
            int4 dv = *(const int4*)(raw + 2 * NEDGE + 4 * e2);
            s0 = sv.x; s1 = sv.z; d0 = dv.x; d1 = dv.z;
        } else {
            int2 sv = *(const int2*)(raw + 2 * e2);
            int2 dv = *(const int2*)(raw + NEDGE + 2 * e2);
            s0 = sv.x; s1 = sv.y; d0 = dv.x; d1 = dv.y;
        }
        csr[atomicAdd(&pos[d0], 1)] = s0;
        csr[atomicAdd(&pos[d1], 1)] = s1;
    }
}

// MFMA GEMM -> hs (PRE-SCALED): hs[n][c] = dinv[n]*(x@W)[n][c] (bf16, flat).
// 64-row tile/block, 4 waves; wave w owns col-tiles 4w..4w+3 with B fragments
// resident in registers (loaded once). Inner loop: ds_read_b128 + MFMA only.
__global__ __launch_bounds__(256, 2) void k_gemm_mfma(
    const float* __restrict__ x, const unsigned short* __restrict__ Wp,
    const float* __restrict__ dinv, unsigned short* __restrict__ hs)
{
    __shared__ unsigned short xs[64 * 256];   // 32 KB, swizzled
    const int tid  = threadIdx.x;
    const int lane = tid & 63;
    const int w    = tid >> 6;
    const int row0 = blockIdx.x * 64;

    bf16x8 breg[4][8];
    #pragma unroll
    for (int t = 0; t < 4; t++)
        #pragma unroll
        for (int kk = 0; kk < 8; kk++)
            breg[t][kk] = ((const bf16x8*)Wp)[((4 * w + t) * 8 + kk) * 64 + lane];

    #pragma unroll
    for (int i = 0; i < 16; i++) {
        int f   = i * 256 + tid;
        int row = f >> 6;
        int c4  = f & 63;
        int grow = row0 + row;
        float4 v = make_float4(0.f, 0.f, 0.f, 0.f);
        if (grow < N_NODES) v = *(const float4*)(x + (size_t)grow * IN_DIM + c4 * 4);
        ushort4 b = { f2b(v.x), f2b(v.y), f2b(v.z), f2b(v.w) };
        unsigned int byte = (unsigned)(row * 512 + c4 * 8);
        byte ^= (unsigned)((row & 7) << 4);
        *(ushort4*)((char*)xs + byte) = b;
    }
    __syncthreads();

    #pragma unroll
    for (int sub = 0; sub < 4; sub++) {
        const int arow = sub * 16 + (lane & 15);
        const unsigned int abase = (unsigned)(arow * 512 + (lane >> 4) * 16);
        const unsigned int axor  = (unsigned)((arow & 7) << 4);

        bf16x8 a[8];
        #pragma unroll
        for (int kk = 0; kk < 8; kk++)
            a[kk] = *(const bf16x8*)((const char*)xs + ((abase + kk * 64) ^ axor));

        f32x4 acc[4];
        #pragma unroll
        for (int t = 0; t < 4; t++) acc[t] = (f32x4){0.f, 0.f, 0.f, 0.f};

        #pragma unroll
        for (int kk = 0; kk < 8; kk++)
            #pragma unroll
            for (int t = 0; t < 4; t++)
                acc[t] = __builtin_amdgcn_mfma_f32_16x16x32_bf16(a[kk], breg[t][kk],
                                                                 acc[t], 0, 0, 0);

        // C/D layout: col=lane&15, row=(lane>>4)*4+reg; scale by dinv on store
        const int rbase = row0 + sub * 16 + (lane >> 4) * 4;
        const int cl = lane & 15;
        float dv[4];
        #pragma unroll
        for (int r = 0; r < 4; r++)
            dv[r] = (rbase + r < N_NODES) ? dinv[rbase + r] : 0.0f;
        #pragma unroll
        for (int t = 0; t < 4; t++) {
            int col = (4 * w + t) * 16 + cl;
            #pragma unroll
            for (int r = 0; r < 4; r++) {
                int row = rbase + r;
                if (row < N_NODES)
                    hs[(size_t)row * ODIM2 + col] = f2b(acc[t][r] * dv[r]);
            }
        }
    }
}

#define ACC4(v) { a0 += b2f((v).x); a1 += b2f((v).y); a2 += b2f((v).z); a3 += b2f((v).w); }

// Wave-per-node pull gather over PRE-SCALED hs: pure accumulate, 16 edges in flight.
// out = dinv_d * (sum_{s in N(d)} hs[s] + hs[d]).
__global__ __launch_bounds__(256) void k_gather(
    const int* __restrict__ row_start, const int* __restrict__ csr,
    const float* __restrict__ dinv, const unsigned short* __restrict__ hs,
    const float* __restrict__ eps, const float* __restrict__ bmu,
    const float* __restrict__ bls, float* __restrict__ z)
{
    const int tid  = threadIdx.x;
    const int n    = blockIdx.x * 4 + (tid >> 6);
    const int lane = tid & 63;
    const float dn = dinv[n];

    float a0, a1, a2, a3;
    {
        ushort4 v = ((const ushort4*)(hs + (size_t)n * ODIM2))[lane];
        a0 = b2f(v.x); a1 = b2f(v.y); a2 = b2f(v.z); a3 = b2f(v.w);
    }

    const int beg = row_start[n];
    const int end = row_start[n + 1];
    int j = beg;
    for (; j < end && (j & 3); j++) {
        int s = csr[j];
        ushort4 v = ((const ushort4*)(hs + (size_t)s * ODIM2))[lane];
        ACC4(v);
    }
    for (; j + 16 <= end; j += 16) {
        int4 sA = *(const int4*)(csr + j);
        int4 sB = *(const int4*)(csr + j + 4);
        int4 sC = *(const int4*)(csr + j + 8);
        int4 sD = *(const int4*)(csr + j + 12);
        ushort4 v0 = ((const ushort4*)(hs + (size_t)sA.x * ODIM2))[lane];
        ushort4 v1 = ((const ushort4*)(hs + (size_t)sA.y * ODIM2))[lane];
        ushort4 v2 = ((const ushort4*)(hs + (size_t)sA.z * ODIM2))[lane];
        ushort4 v3 = ((const ushort4*)(hs + (size_t)sA.w * ODIM2))[lane];
        ushort4 v4 = ((const ushort4*)(hs + (size_t)sB.x * ODIM2))[lane];
        ushort4 v5 = ((const ushort4*)(hs + (size_t)sB.y * ODIM2))[lane];
        ushort4 v6 = ((const ushort4*)(hs + (size_t)sB.z * ODIM2))[lane];
        ushort4 v7 = ((const ushort4*)(hs + (size_t)sB.w * ODIM2))[lane];
        ushort4 v8 = ((const ushort4*)(hs + (size_t)sC.x * ODIM2))[lane];
        ushort4 v9 = ((const ushort4*)(hs + (size_t)sC.y * ODIM2))[lane];
        ushort4 va = ((const ushort4*)(hs + (size_t)sC.z * ODIM2))[lane];
        ushort4 vb = ((const ushort4*)(hs + (size_t)sC.w * ODIM2))[lane];
        ushort4 vc = ((const ushort4*)(hs + (size_t)sD.x * ODIM2))[lane];
        ushort4 vd = ((const ushort4*)(hs + (size_t)sD.y * ODIM2))[lane];
        ushort4 ve = ((const ushort4*)(hs + (size_t)sD.z * ODIM2))[lane];
        ushort4 vf = ((const ushort4*)(hs + (size_t)sD.w * ODIM2))[lane];
        ACC4(v0); ACC4(v1); ACC4(v2); ACC4(v3);
        ACC4(v4); ACC4(v5); ACC4(v6); ACC4(v7);
        ACC4(v8); ACC4(v9); ACC4(va); ACC4(vb);
        ACC4(vc); ACC4(vd); ACC4(ve); ACC4(vf);
    }
    if (j + 8 <= end) {
        int4 sA = *(const int4*)(csr + j);
        int4 sB = *(const int4*)(csr + j + 4);
        ushort4 v0 = ((const ushort4*)(hs + (size_t)sA.x * ODIM2))[lane];
        ushort4 v1 = ((const ushort4*)(hs + (size_t)sA.y * ODIM2))[lane];
        ushort4 v2 = ((const ushort4*)(hs + (size_t)sA.z * ODIM2))[lane];
        ushort4 v3 = ((const ushort4*)(hs + (size_t)sA.w * ODIM2))[lane];
        ushort4 v4 = ((const ushort4*)(hs + (size_t)sB.x * ODIM2))[lane];
        ushort4 v5 = ((const ushort4*)(hs + (size_t)sB.y * ODIM2))[lane];
        ushort4 v6 = ((const ushort4*)(hs + (size_t)sB.z * ODIM2))[lane];
        ushort4 v7 = ((const ushort4*)(hs + (size_t)sB.w * ODIM2))[lane];
        ACC4(v0); ACC4(v1); ACC4(v2); ACC4(v3);
        ACC4(v4); ACC4(v5); ACC4(v6); ACC4(v7);
        j += 8;
    }
    if (j + 4 <= end) {
        int4 sA = *(const int4*)(csr + j);
        ushort4 v0 = ((const ushort4*)(hs + (size_t)sA.x * ODIM2))[lane];
        ushort4 v1 = ((const ushort4*)(hs + (size_t)sA.y * ODIM2))[lane];
        ushort4 v2 = ((const ushort4*)(hs + (size_t)sA.z * ODIM2))[lane];
        ushort4 v3 = ((const ushort4*)(hs + (size_t)sA.w * ODIM2))[lane];
        ACC4(v0); ACC4(v1); ACC4(v2); ACC4(v3);
        j += 4;
    }
    for (; j < end; j++) {
        int s = csr[j];
        ushort4 v = ((const ushort4*)(hs + (size_t)s * ODIM2))[lane];
        ACC4(v);
    }

    float l0 = __shfl(a0, lane | 32);
    float l1 = __shfl(a1, lane | 32);
    float l2 = __shfl(a2, lane | 32);
    float l3 = __shfl(a3, lane | 32);

    if (lane < 32) {
        int c = lane * 4;
        float4 ep = *(const float4*)(eps + (size_t)n * OUT_DIM + c);
        float4 bm = *(const float4*)(bmu + c);
        float4 bl = *(const float4*)(bls + c);
        float4 o;
        o.x = dn * a0 + bm.x + ep.x * expf(fminf(dn * l0 + bl.x, MAX_LOGSTD));
        o.y = dn * a1 + bm.y + ep.y * expf(fminf(dn * l1 + bl.y, MAX_LOGSTD));
        o.z = dn * a2 + bm.z + ep.z * expf(fminf(dn * l2 + bl.z, MAX_LOGSTD));
        o.w = dn * a3 + bm.w + ep.w * expf(fminf(dn * l3 + bl.w, MAX_LOGSTD));
        *(float4*)(z + (size_t)n * OUT_DIM + c) = o;
    }
}

extern "C" void kernel_launch(void* const* d_in, const int* in_sizes, int n_in,
                              void* d_out, int out_size, void* d_ws, size_t ws_size,
                              hipStream_t stream) {
    const float* x   = (const float*)d_in[0];
    const int*   ei  = (const int*)  d_in[1];
    const float* Wmu = (const float*)d_in[2];
    const float* bmu = (const float*)d_in[3];
    const float* Wls = (const float*)d_in[4];
    const float* bls = (const float*)d_in[5];
    const float* eps = (const float*)d_in[6];
    float* z = (float*)d_out;

    char* ws = (char*)d_ws;
    size_t off = 0;
    auto alloc = [&](size_t bytes) {
        void* p = ws + off;
        off += (bytes + 255) & ~(size_t)255;
        return p;
    };
    int*   cnt       = (int*)  alloc((size_t)N_NODES * 4);
    float* dinv      = (float*)alloc((size_t)N_NODES * 4);
    int*   row_start = (int*)  alloc((size_t)(N_NODES + 1) * 4);
    int*   pos       = (int*)  alloc((size_t)N_NODES * 4);
    int*   csr       = (int*)  alloc((size_t)NEDGE * 4);
    int*   bsum      = (int*)  alloc((size_t)NBLK * 4);
    int*   boff      = (int*)  alloc((size_t)NBLK * 4);
    unsigned short* hs = (unsigned short*)alloc((size_t)N_NODES * ODIM2 * 2);
    unsigned short* Wp = (unsigned short*)alloc((size_t)65536 * 2);

    hipMemsetAsync(cnt, 0, N_NODES * sizeof(int), stream);

    k_count     <<<(NEDGE / 2 + 255) / 256, 256, 0, stream>>>(ei, cnt);
    k_blocksum  <<<NBLK,                    256, 0, stream>>>(cnt, bsum);
    k_scanblocks<<<1,                       256, 0, stream>>>(bsum, boff);
    k_apply     <<<NBLK,                    256, 0, stream>>>(cnt, boff, row_start,
                                                              pos, dinv, Wmu, Wls, Wp);
    k_fill      <<<(NEDGE / 2 + 255) / 256, 256, 0, stream>>>(ei, pos, csr);
    k_gemm_mfma <<<(N_NODES + 63) / 64,     256, 0, stream>>>(x, Wp, dinv, hs);
    k_gather    <<<N_NODES / 4,             256, 0, stream>>>(row_start, csr, dinv, hs,
                                                              eps, bmu, bls, z);
}

// Round 11
// 196.452 us; speedup vs baseline: 2.4368x; 1.0830x over previous
//
#include <hip/hip_runtime.h>
#include <hip/hip_bf16.h>

#define N_NODES 50000
#define IN_DIM 256
#define OUT_DIM 128
#define ODIM2 256        // mu(128) + logstd(128) concatenated
#define NEDGE 800000
#define MAX_LOGSTD 10.0f
#define NBLK 196         // ceil(50000/256)

typedef short bf16x8 __attribute__((ext_vector_type(8)));
typedef float f32x4  __attribute__((ext_vector_type(4)));

__device__ __forceinline__ float b2f(unsigned short u) {
    union { unsigned int i; float f; } v; v.i = ((unsigned int)u) << 16; return v.f;
}
__device__ __forceinline__ unsigned short f2b(float f) {
    union { float f; unsigned int i; } v; v.f = f;
    unsigned int x = v.i;
    unsigned int r = (x + 0x7fffu + ((x >> 16) & 1u)) >> 16;
    return (unsigned short)r;
}
__device__ __forceinline__ bool edges_are_i64(const int* raw) {
    bool is64 = true;
    #pragma unroll
    for (int i = 0; i < 8; i++) if (raw[2 * i + 1] != 0) is64 = false;
    return is64;
}

// Convert raw edges (int64/int32 auto-detect) -> ei32, + dst histogram.
// 2 edges/thread, int4 vectorized raw reads, int2 coalesced ei32 writes.
__global__ void k_conv_count(const int* __restrict__ raw, int* __restrict__ ei32,
                             int* __restrict__ cnt) {
    bool is64 = edges_are_i64(raw);
    int e2 = blockIdx.x * blockDim.x + threadIdx.x;   // edge-pair index
    if (e2 < NEDGE / 2) {
        int s0, s1, d0, d1;
        if (is64) {
            int4 sv = *(const int4*)(raw + 4 * e2);
            int4 dv = *(const int4*)(raw + 2 * NEDGE + 4 * e2);
            s0 = sv.x; s1 = sv.z; d0 = dv.x; d1 = dv.z;
        } else {
            int2 sv = *(const int2*)(raw + 2 * e2);
            int2 dv = *(const int2*)(raw + NEDGE + 2 * e2);
            s0 = sv.x; s1 = sv.y; d0 = dv.x; d1 = dv.y;
        }
        *(int2*)(ei32 + 2 * e2)         = make_int2(s0, s1);
        *(int2*)(ei32 + NEDGE + 2 * e2) = make_int2(d0, d1);
        atomicAdd(&cnt[d0], 1);
        atomicAdd(&cnt[d1], 1);
    }
}

// Phase 1: per-block (256 counts) sums
__global__ __launch_bounds__(256) void k_blocksum(const int* __restrict__ cnt,
                                                  int* __restrict__ bsum) {
    int idx = blockIdx.x * 256 + threadIdx.x;
    int v = (idx < N_NODES) ? cnt[idx] : 0;
    #pragma unroll
    for (int o = 32; o > 0; o >>= 1) v += __shfl_down(v, o);
    __shared__ int wsum[4];
    int lane = threadIdx.x & 63, w = threadIdx.x >> 6;
    if (lane == 0) wsum[w] = v;
    __syncthreads();
    if (threadIdx.x == 0) bsum[blockIdx.x] = wsum[0] + wsum[1] + wsum[2] + wsum[3];
}

// Phase 2: scan 196 block sums -> exclusive block offsets
__global__ __launch_bounds__(256) void k_scanblocks(const int* __restrict__ bsum,
                                                    int* __restrict__ boff) {
    __shared__ int s[256];
    int t = threadIdx.x;
    s[t] = (t < NBLK) ? bsum[t] : 0;
    __syncthreads();
    for (int o = 1; o < 256; o <<= 1) {
        int v = (t >= o) ? s[t - o] : 0;
        __syncthreads();
        s[t] += v;
        __syncthreads();
    }
    if (t < NBLK) boff[t] = (t == 0) ? 0 : s[t - 1];
}

// Phase 3: in-block exclusive scan + offset -> row_start, pos, dinv.
// Blocks 0..31 additionally pack concat(Wmu,Wls) into B-fragment bf16 layout:
// Wp[((tile*8+kk)*64+lane)*8 + j] = W[kk*32+(lane>>4)*8+j][tile*16+(lane&15)]
__global__ __launch_bounds__(256) void k_apply(const int* __restrict__ cnt,
                                               const int* __restrict__ boff,
                                               int* __restrict__ row_start,
                                               int* __restrict__ pos,
                                               float* __restrict__ dinv,
                                               const float* __restrict__ Wmu,
                                               const float* __restrict__ Wls,
                                               unsigned short* __restrict__ Wp) {
    __shared__ int s[256];
    int t = threadIdx.x;
    int idx = blockIdx.x * 256 + t;
    int c = (idx < N_NODES) ? cnt[idx] : 0;
    s[t] = c;
    __syncthreads();
    for (int o = 1; o < 256; o <<= 1) {
        int v = (t >= o) ? s[t - o] : 0;
        __syncthreads();
        s[t] += v;
        __syncthreads();
    }
    int excl = boff[blockIdx.x] + s[t] - c;
    if (idx < N_NODES) {
        row_start[idx] = excl;
        pos[idx] = excl;
        dinv[idx] = rsqrtf((float)c + 1.0f);
    }
    if (idx == N_NODES - 1) row_start[N_NODES] = NEDGE;

    if (blockIdx.x < 32) {            // fused weight conversion (8192 jobs)
        int i = blockIdx.x * 256 + t;
        int lane = i & 63;
        int kk   = (i >> 6) & 7;
        int tile = i >> 9;
        int k0 = kk * 32 + (lane >> 4) * 8;
        int n  = tile * 16 + (lane & 15);
        const float* W = (n < 128) ? (Wmu + n) : (Wls + (n - 128));
        unsigned short o[8];
        #pragma unroll
        for (int j = 0; j < 8; j++) o[j] = f2b(W[(size_t)(k0 + j) * OUT_DIM]);
        ushort4 lo = { o[0], o[1], o[2], o[3] };
        ushort4 hi = { o[4], o[5], o[6], o[7] };
        *(ushort4*)(Wp + (size_t)i * 8)     = lo;
        *(ushort4*)(Wp + (size_t)i * 8 + 4) = hi;
    }
}

// Bin edges by dst from ei32 (coalesced int4 reads, 4 edges/thread)
__global__ void k_fill(const int* __restrict__ ei32, int* __restrict__ pos,
                       int* __restrict__ csr) {
    int e4 = blockIdx.x * blockDim.x + threadIdx.x;
    if (e4 < NEDGE / 4) {
        int4 sv = *(const int4*)(ei32 + 4 * e4);
        int4 dv = *(const int4*)(ei32 + NEDGE + 4 * e4);
        csr[atomicAdd(&pos[dv.x], 1)] = sv.x;
        csr[atomicAdd(&pos[dv.y], 1)] = sv.y;
        csr[atomicAdd(&pos[dv.z], 1)] = sv.z;
        csr[atomicAdd(&pos[dv.w], 1)] = sv.w;
    }
}

// MFMA GEMM -> hs (PRE-SCALED): hs[n][c] = dinv[n]*(x@W)[n][c] (bf16, flat).
// 64-row tile/block, 4 waves; wave w owns col-tiles 4w..4w+3 with B fragments
// resident in registers (loaded once). Inner loop: ds_read_b128 + MFMA only.
__global__ __launch_bounds__(256, 2) void k_gemm_mfma(
    const float* __restrict__ x, const unsigned short* __restrict__ Wp,
    const float* __restrict__ dinv, unsigned short* __restrict__ hs)
{
    __shared__ unsigned short xs[64 * 256];   // 32 KB, swizzled
    const int tid  = threadIdx.x;
    const int lane = tid & 63;
    const int w    = tid >> 6;
    const int row0 = blockIdx.x * 64;

    bf16x8 breg[4][8];
    #pragma unroll
    for (int t = 0; t < 4; t++)
        #pragma unroll
        for (int kk = 0; kk < 8; kk++)
            breg[t][kk] = ((const bf16x8*)Wp)[((4 * w + t) * 8 + kk) * 64 + lane];

    #pragma unroll
    for (int i = 0; i < 16; i++) {
        int f   = i * 256 + tid;
        int row = f >> 6;
        int c4  = f & 63;
        int grow = row0 + row;
        float4 v = make_float4(0.f, 0.f, 0.f, 0.f);
        if (grow < N_NODES) v = *(const float4*)(x + (size_t)grow * IN_DIM + c4 * 4);
        ushort4 b = { f2b(v.x), f2b(v.y), f2b(v.z), f2b(v.w) };
        unsigned int byte = (unsigned)(row * 512 + c4 * 8);
        byte ^= (unsigned)((row & 7) << 4);
        *(ushort4*)((char*)xs + byte) = b;
    }
    __syncthreads();

    #pragma unroll
    for (int sub = 0; sub < 4; sub++) {
        const int arow = sub * 16 + (lane & 15);
        const unsigned int abase = (unsigned)(arow * 512 + (lane >> 4) * 16);
        const unsigned int axor  = (unsigned)((arow & 7) << 4);

        bf16x8 a[8];
        #pragma unroll
        for (int kk = 0; kk < 8; kk++)
            a[kk] = *(const bf16x8*)((const char*)xs + ((abase + kk * 64) ^ axor));

        f32x4 acc[4];
        #pragma unroll
        for (int t = 0; t < 4; t++) acc[t] = (f32x4){0.f, 0.f, 0.f, 0.f};

        #pragma unroll
        for (int kk = 0; kk < 8; kk++)
            #pragma unroll
            for (int t = 0; t < 4; t++)
                acc[t] = __builtin_amdgcn_mfma_f32_16x16x32_bf16(a[kk], breg[t][kk],
                                                                 acc[t], 0, 0, 0);

        // C/D layout: col=lane&15, row=(lane>>4)*4+reg; scale by dinv on store
        const int rbase = row0 + sub * 16 + (lane >> 4) * 4;
        const int cl = lane & 15;
        float dv[4];
        #pragma unroll
        for (int r = 0; r < 4; r++)
            dv[r] = (rbase + r < N_NODES) ? dinv[rbase + r] : 0.0f;
        #pragma unroll
        for (int t = 0; t < 4; t++) {
            int col = (4 * w + t) * 16 + cl;
            #pragma unroll
            for (int r = 0; r < 4; r++) {
                int row = rbase + r;
                if (row < N_NODES)
                    hs[(size_t)row * ODIM2 + col] = f2b(acc[t][r] * dv[r]);
            }
        }
    }
}

#define ACC4(v) { a0 += b2f((v).x); a1 += b2f((v).y); a2 += b2f((v).z); a3 += b2f((v).w); }

// Wave-per-node pull gather over PRE-SCALED hs: pure accumulate, 8 edges in
// flight (R8 config: VGPR 28, occupancy ~67% -- measured best).
// out = dinv_d * (sum_{s in N(d)} hs[s] + hs[d]).
__global__ __launch_bounds__(256) void k_gather(
    const int* __restrict__ row_start, const int* __restrict__ csr,
    const float* __restrict__ dinv, const unsigned short* __restrict__ hs,
    const float* __restrict__ eps, const float* __restrict__ bmu,
    const float* __restrict__ bls, float* __restrict__ z)
{
    const int tid  = threadIdx.x;
    const int n    = blockIdx.x * 4 + (tid >> 6);
    const int lane = tid & 63;
    const float dn = dinv[n];

    float a0, a1, a2, a3;
    {   // self-loop seed: hs[n] (scaled by dn at the end)
        ushort4 v = ((const ushort4*)(hs + (size_t)n * ODIM2))[lane];
        a0 = b2f(v.x); a1 = b2f(v.y); a2 = b2f(v.z); a3 = b2f(v.w);
    }

    const int beg = row_start[n];
    const int end = row_start[n + 1];
    int j = beg;
    for (; j < end && (j & 3); j++) {              // align to int4
        int s = csr[j];
        ushort4 v = ((const ushort4*)(hs + (size_t)s * ODIM2))[lane];
        ACC4(v);
    }
    for (; j + 8 <= end; j += 8) {                 // 8 gathers in flight
        int4 sA = *(const int4*)(csr + j);
        int4 sB = *(const int4*)(csr + j + 4);
        ushort4 v0 = ((const ushort4*)(hs + (size_t)sA.x * ODIM2))[lane];
        ushort4 v1 = ((const ushort4*)(hs + (size_t)sA.y * ODIM2))[lane];
        ushort4 v2 = ((const ushort4*)(hs + (size_t)sA.z * ODIM2))[lane];
        ushort4 v3 = ((const ushort4*)(hs + (size_t)sA.w * ODIM2))[lane];
        ushort4 v4 = ((const ushort4*)(hs + (size_t)sB.x * ODIM2))[lane];
        ushort4 v5 = ((const ushort4*)(hs + (size_t)sB.y * ODIM2))[lane];
        ushort4 v6 = ((const ushort4*)(hs + (size_t)sB.z * ODIM2))[lane];
        ushort4 v7 = ((const ushort4*)(hs + (size_t)sB.w * ODIM2))[lane];
        ACC4(v0); ACC4(v1); ACC4(v2); ACC4(v3);
        ACC4(v4); ACC4(v5); ACC4(v6); ACC4(v7);
    }
    if (j + 4 <= end) {
        int4 sA = *(const int4*)(csr + j);
        ushort4 v0 = ((const ushort4*)(hs + (size_t)sA.x * ODIM2))[lane];
        ushort4 v1 = ((const ushort4*)(hs + (size_t)sA.y * ODIM2))[lane];
        ushort4 v2 = ((const ushort4*)(hs + (size_t)sA.z * ODIM2))[lane];
        ushort4 v3 = ((const ushort4*)(hs + (size_t)sA.w * ODIM2))[lane];
        ACC4(v0); ACC4(v1); ACC4(v2); ACC4(v3);
        j += 4;
    }
    for (; j < end; j++) {
        int s = csr[j];
        ushort4 v = ((const ushort4*)(hs + (size_t)s * ODIM2))[lane];
        ACC4(v);
    }

    float l0 = __shfl(a0, lane | 32);
    float l1 = __shfl(a1, lane | 32);
    float l2 = __shfl(a2, lane | 32);
    float l3 = __shfl(a3, lane | 32);

    if (lane < 32) {
        int c = lane * 4;
        float4 ep = *(const float4*)(eps + (size_t)n * OUT_DIM + c);
        float4 bm = *(const float4*)(bmu + c);
        float4 bl = *(const float4*)(bls + c);
        float4 o;
        o.x = dn * a0 + bm.x + ep.x * expf(fminf(dn * l0 + bl.x, MAX_LOGSTD));
        o.y = dn * a1 + bm.y + ep.y * expf(fminf(dn * l1 + bl.y, MAX_LOGSTD));
        o.z = dn * a2 + bm.z + ep.z * expf(fminf(dn * l2 + bl.z, MAX_LOGSTD));
        o.w = dn * a3 + bm.w + ep.w * expf(fminf(dn * l3 + bl.w, MAX_LOGSTD));
        *(float4*)(z + (size_t)n * OUT_DIM + c) = o;
    }
}

extern "C" void kernel_launch(void* const* d_in, const int* in_sizes, int n_in,
                              void* d_out, int out_size, void* d_ws, size_t ws_size,
                              hipStream_t stream) {
    const float* x   = (const float*)d_in[0];
    const int*   ei  = (const int*)  d_in[1];
    const float* Wmu = (const float*)d_in[2];
    const float* bmu = (const float*)d_in[3];
    const float* Wls = (const float*)d_in[4];
    const float* bls = (const float*)d_in[5];
    const float* eps = (const float*)d_in[6];
    float* z = (float*)d_out;

    char* ws = (char*)d_ws;
    size_t off = 0;
    auto alloc = [&](size_t bytes) {
        void* p = ws + off;
        off += (bytes + 255) & ~(size_t)255;
        return p;
    };
    int*   ei32      = (int*)  alloc((size_t)2 * NEDGE * 4);
    int*   cnt       = (int*)  alloc((size_t)N_NODES * 4);
    float* dinv      = (float*)alloc((size_t)N_NODES * 4);
    int*   row_start = (int*)  alloc((size_t)(N_NODES + 1) * 4);
    int*   pos       = (int*)  alloc((size_t)N_NODES * 4);
    int*   csr       = (int*)  alloc((size_t)NEDGE * 4);
    int*   bsum      = (int*)  alloc((size_t)NBLK * 4);
    int*   boff      = (int*)  alloc((size_t)NBLK * 4);
    unsigned short* hs = (unsigned short*)alloc((size_t)N_NODES * ODIM2 * 2);
    unsigned short* Wp = (unsigned short*)alloc((size_t)65536 * 2);

    hipMemsetAsync(cnt, 0, N_NODES * sizeof(int), stream);

    k_conv_count<<<(NEDGE / 2 + 255) / 256, 256, 0, stream>>>(ei, ei32, cnt);
    k_blocksum  <<<NBLK,                    256, 0, stream>>>(cnt, bsum);
    k_scanblocks<<<1,                       256, 0, stream>>>(bsum, boff);
    k_apply     <<<NBLK,                    256, 0, stream>>>(cnt, boff, row_start,
                                                              pos, dinv, Wmu, Wls, Wp);
    k_fill      <<<(NEDGE / 4 + 255) / 256, 256, 0, stream>>>(ei32, pos, csr);
    k_gemm_mfma <<<(N_NODES + 63) / 64,     256, 0, stream>>>(x, Wp, dinv, hs);
    k_gather    <<<N_NODES / 4,             256, 0, stream>>>(row_start, csr, dinv, hs,
                                                              eps, bmu, bls, z);
}